// Round 10
// baseline (157.008 us; speedup 1.0000x reference)
//
#include <hip/hip_runtime.h>

#define NB 262144
#define NJ 24
#define TB 64              // ONE wave per block
#define NBATCH 16          // batches per block; 4 threads (rows) per batch
#define NPH (NJ / 2)

typedef float fvec4 __attribute__((ext_vector_type(4)));
typedef float fvec2 __attribute__((ext_vector_type(2)));

__global__ __launch_bounds__(TB, 2) void fk_kernel(
    const float* __restrict__ rot6,   // [NB][NJ][6]
    const float* __restrict__ pos,    // [NB][NJ][3]
    float* __restrict__ coords,       // [NB][NJ][3]
    float* __restrict__ tf)           // [NB][NJ][4][4]
{
    // LDS (13824 B -> ~11 single-wave blocks/CU):
    //   [0,     9216)  sin_rot fvec4[576]  phase-major [12 t][16 bl][3 k]
    //                  | epilogue overlay: scoord [16][73] floats (4672 B)
    //   [9216, 13824)  sin_pos fvec2[576]  [12 t][16 bl][3 k]
    __shared__ __align__(16) char smem[13824];
    fvec4* sin_rot = (fvec4*)smem;
    fvec2* sin_pos = (fvec2*)(smem + 9216);
    float* scoord  = (float*)smem;

    const int tid = threadIdx.x;
    const int bl  = tid & 15;     // batch within block
    const int r   = tid >> 4;     // row 0..3
    const int b0  = blockIdx.x * NBATCH;

    constexpr int P[NJ] = {0,0,0,0,1,2,3,4,5,6,7,8,9,9,9,12,13,14,16,17,18,19,20,21};

    const fvec4* __restrict__ grot4 = (const fvec4*)rot6;   // 36 fvec4 / batch
    const fvec2* __restrict__ gpos2 = (const fvec2*)pos;    // 36 fvec2 / batch
    fvec4* __restrict__ gtf4 = (fvec4*)tf;                  // 96 fvec4 / batch
    fvec2* __restrict__ gco2 = (fvec2*)coords;              // 36 fvec2 / batch

    // ---- one-shot input staging: perfectly linear global sweep, zero refetch ----
    #pragma unroll
    for (int i = 0; i < 9; ++i) {
        int q  = i * TB + tid;                 // [0, 576) fvec4
        int bq = q / 36, rem = q - bq * 36;    // batch, fvec4-within-batch
        int t  = rem / 3, k = rem - t * 3;     // phase, fvec4-within-phase
        sin_rot[t * 48 + bq * 3 + k] = grot4[(size_t)(b0 + bq) * 36 + rem];
    }
    #pragma unroll
    for (int i = 0; i < 9; ++i) {
        int q  = i * TB + tid;                 // [0, 576) fvec2
        int bq = q / 36, rem = q - bq * 36;
        int t  = rem / 3, k = rem - t * 3;
        sin_pos[t * 48 + bq * 3 + k] = gpos2[(size_t)(b0 + bq) * 36 + rem];
    }
    __syncthreads();   // single-wave: lowers to waitcnt, ~free

    // this thread's row r of G[j]; [0..2] frontier-live, [3] (=w) lives to epilogue
    float Grow[NJ][4];

    #pragma unroll
    for (int t = 0; t < NPH; ++t) {
        // own-batch fragment (same-addr broadcast across r-groups; 2-way max across bl)
        const fvec4 r0 = sin_rot[t * 48 + bl * 3 + 0];
        const fvec4 r1 = sin_rot[t * 48 + bl * 3 + 1];
        const fvec4 r2 = sin_rot[t * 48 + bl * 3 + 2];
        const fvec2 p0 = sin_pos[t * 48 + bl * 3 + 0];
        const fvec2 p1 = sin_pos[t * 48 + bl * 3 + 1];
        const fvec2 p2 = sin_pos[t * 48 + bl * 3 + 2];

        #pragma unroll
        for (int jj = 0; jj < 2; ++jj) {
            const int j = 2 * t + jj;
            const float a1x = jj ? r1.z : r0.x;
            const float a1y = jj ? r1.w : r0.y;
            const float a1z = jj ? r2.x : r0.z;
            const float a2x = jj ? r2.y : r0.w;
            const float a2y = jj ? r2.z : r1.x;
            const float a2z = jj ? r2.w : r1.y;
            const float px  = jj ? p1.y : p0.x;
            const float py  = jj ? p2.x : p0.y;
            const float pz  = jj ? p2.y : p1.x;

            // 6D -> rotation (Gram-Schmidt), redundantly per row-thread (VALU has slack)
            const float inv1 = rsqrtf(a1x*a1x + a1y*a1y + a1z*a1z);
            const float b1x = a1x*inv1, b1y = a1y*inv1, b1z = a1z*inv1;
            const float d   = b1x*a2x + b1y*a2y + b1z*a2z;
            const float c2x = a2x - d*b1x, c2y = a2y - d*b1y, c2z = a2z - d*b1z;
            const float inv2 = rsqrtf(c2x*c2x + c2y*c2y + c2z*c2z);
            const float b2x = c2x*inv2, b2y = c2y*inv2, b2z = c2z*inv2;
            const float b3x = b1y*b2z - b1z*b2y;
            const float b3y = b1z*b2x - b1x*b2z;
            const float b3z = b1x*b2y - b1y*b2x;

            fvec4 out;
            if (j == 0) {
                // row select; r==3 -> (0,0,0,1), preserved by the update math forever
                out.x = (r == 0) ? b1x : (r == 1) ? b2x : (r == 2) ? b3x : 0.f;
                out.y = (r == 0) ? b1y : (r == 1) ? b2y : (r == 2) ? b3y : 0.f;
                out.z = (r == 0) ? b1z : (r == 1) ? b2z : (r == 2) ? b3z : 0.f;
                out.w = (r == 0) ? px  : (r == 1) ? py  : (r == 2) ? pz  : 1.f;
            } else {
                const int p = P[j];
                const float g0 = Grow[p][0], g1 = Grow[p][1], g2 = Grow[p][2], g3 = Grow[p][3];
                out.x = g0*b1x + g1*b2x + g2*b3x;
                out.y = g0*b1y + g1*b2y + g2*b3y;
                out.z = g0*b1z + g1*b2z + g2*b3z;
                out.w = g0*px  + g1*py  + g2*pz  + g3;
            }
            Grow[j][0] = out.x; Grow[j][1] = out.y;
            Grow[j][2] = out.z; Grow[j][3] = out.w;

            // DIRECT store: wave covers 16 batches x 4 rows = 16 fully-written
            // 64 B sectors (sector-granular at L2 -> no RMW, no tile needed)
            gtf4[(size_t)(b0 + bl) * 96 + t * 8 + jj * 4 + r] = out;
        }
    }
    __syncthreads();   // staging reads done before scoord overlay (~free)

    // ---- epilogue: coords via LDS transpose; per-block output perfectly linear ----
    if (r < 3) {
        #pragma unroll
        for (int j = 0; j < NJ; ++j)
            scoord[bl * 73 + j * 3 + r] = Grow[j][3];
    }
    __syncthreads();
    #pragma unroll
    for (int i = 0; i < 9; ++i) {
        int fq = i * TB + tid;                // [0, 576) fvec2
        int br = fq / 36, k2 = fq - br * 36;
        fvec2 v;
        v.x = scoord[br * 73 + 2 * k2 + 0];
        v.y = scoord[br * 73 + 2 * k2 + 1];
        gco2[(size_t)(b0 + br) * 36 + k2] = v;
    }
}

extern "C" void kernel_launch(void* const* d_in, const int* in_sizes, int n_in,
                              void* d_out, int out_size, void* d_ws, size_t ws_size,
                              hipStream_t stream) {
    const float* rot6 = (const float*)d_in[0];
    const float* pos  = (const float*)d_in[1];
    float* coords = (float*)d_out;                       // B*J*3
    float* tf     = (float*)d_out + (size_t)NB * NJ * 3; // B*J*16

    fk_kernel<<<dim3(NB / NBATCH), dim3(TB), 0, stream>>>(rot6, pos, coords, tf);
}

// Round 11
// 137.763 us; speedup vs baseline: 1.1397x; 1.1397x over previous
//
#include <hip/hip_runtime.h>

#define NB 262144
#define NJ 24
#define TB 128
#define NBATCH 32          // batches per block; 4 threads (rows) per batch
#define NPH (NJ / 2)

typedef float fvec4 __attribute__((ext_vector_type(4)));
typedef float fvec2 __attribute__((ext_vector_type(2)));

__global__ __launch_bounds__(TB, 2) void fk_kernel(
    const float* __restrict__ rot6,   // [NB][NJ][6]
    const float* __restrict__ pos,    // [NB][NJ][3]
    float* __restrict__ coords,       // [NB][NJ][3]
    float* __restrict__ tf)           // [NB][NJ][4][4]
{
    // LDS map (31744 B -> 5 blocks/CU, 10 waves):
    //   [0,     18432)  sin_rot fvec4[1152]  phase-major [12 t][32 bl][3 k]
    //                   | epilogue overlay: scoord [32][73] floats (9344 B)
    //   [18432, 27648)  sin_pos fvec2[1152]  [12 t][32 bl][3 k]
    //   [27648, 31744)  stf fvec4[256]       single-buffered tile [32 bl][8 s]
    __shared__ __align__(16) char smem[31744];
    fvec4* sin_rot = (fvec4*)smem;
    fvec2* sin_pos = (fvec2*)(smem + 18432);
    fvec4* stf     = (fvec4*)(smem + 27648);
    float* scoord  = (float*)smem;

    const int tid = threadIdx.x;
    const int bl  = tid & 31;     // batch within block
    const int r   = tid >> 5;     // row 0..3
    const int b0  = blockIdx.x * NBATCH;

    constexpr int P[NJ] = {0,0,0,0,1,2,3,4,5,6,7,8,9,9,9,12,13,14,16,17,18,19,20,21};

    const fvec4* __restrict__ grot4 = (const fvec4*)rot6;   // 36 fvec4 / batch
    const fvec2* __restrict__ gpos2 = (const fvec2*)pos;    // 36 fvec2 / batch
    fvec4* __restrict__ gtf4 = (fvec4*)tf;                  // 96 fvec4 / batch
    fvec2* __restrict__ gco2 = (fvec2*)coords;              // 36 fvec2 / batch

    // ---- one-shot input staging: perfectly linear global sweep, zero refetch ----
    #pragma unroll
    for (int i = 0; i < 9; ++i) {
        int q  = i * TB + tid;                 // [0, 1152) fvec4
        int bq = q / 36, rem = q - bq * 36;    // batch, fvec4-within-batch
        int t  = rem / 3, k = rem - t * 3;     // phase, fvec4-within-phase
        sin_rot[t * 96 + bq * 3 + k] = grot4[(size_t)(b0 + bq) * 36 + rem];
    }
    #pragma unroll
    for (int i = 0; i < 9; ++i) {
        int q  = i * TB + tid;                 // [0, 1152) fvec2
        int bq = q / 36, rem = q - bq * 36;
        int t  = rem / 3, k = rem - t * 3;
        sin_pos[t * 96 + bq * 3 + k] = gpos2[(size_t)(b0 + bq) * 36 + rem];
    }
    __syncthreads();

    // this thread's row r of G[j]; [0..2] frontier-live, [3] (=w) lives to epilogue
    float Grow[NJ][4];

    #pragma unroll
    for (int t = 0; t < NPH; ++t) {
        // own-batch fragment (stride 48 B / 24 B across lanes: uniform bank spread)
        const fvec4 r0 = sin_rot[t * 96 + bl * 3 + 0];
        const fvec4 r1 = sin_rot[t * 96 + bl * 3 + 1];
        const fvec4 r2 = sin_rot[t * 96 + bl * 3 + 2];
        const fvec2 p0 = sin_pos[t * 96 + bl * 3 + 0];
        const fvec2 p1 = sin_pos[t * 96 + bl * 3 + 1];
        const fvec2 p2 = sin_pos[t * 96 + bl * 3 + 2];

        #pragma unroll
        for (int jj = 0; jj < 2; ++jj) {
            const int j = 2 * t + jj;
            const float a1x = jj ? r1.z : r0.x;
            const float a1y = jj ? r1.w : r0.y;
            const float a1z = jj ? r2.x : r0.z;
            const float a2x = jj ? r2.y : r0.w;
            const float a2y = jj ? r2.z : r1.x;
            const float a2z = jj ? r2.w : r1.y;
            const float px  = jj ? p1.y : p0.x;
            const float py  = jj ? p2.x : p0.y;
            const float pz  = jj ? p2.y : p1.x;

            // 6D -> rotation (Gram-Schmidt), redundantly per row-thread (VALU has slack)
            const float inv1 = rsqrtf(a1x*a1x + a1y*a1y + a1z*a1z);
            const float b1x = a1x*inv1, b1y = a1y*inv1, b1z = a1z*inv1;
            const float d   = b1x*a2x + b1y*a2y + b1z*a2z;
            const float c2x = a2x - d*b1x, c2y = a2y - d*b1y, c2z = a2z - d*b1z;
            const float inv2 = rsqrtf(c2x*c2x + c2y*c2y + c2z*c2z);
            const float b2x = c2x*inv2, b2y = c2y*inv2, b2z = c2z*inv2;
            const float b3x = b1y*b2z - b1z*b2y;
            const float b3y = b1z*b2x - b1x*b2z;
            const float b3z = b1x*b2y - b1y*b2x;

            fvec4 out;
            if (j == 0) {
                // row select; r==3 -> (0,0,0,1), preserved by the update math forever
                out.x = (r == 0) ? b1x : (r == 1) ? b2x : (r == 2) ? b3x : 0.f;
                out.y = (r == 0) ? b1y : (r == 1) ? b2y : (r == 2) ? b3y : 0.f;
                out.z = (r == 0) ? b1z : (r == 1) ? b2z : (r == 2) ? b3z : 0.f;
                out.w = (r == 0) ? px  : (r == 1) ? py  : (r == 2) ? pz  : 1.f;
            } else {
                const int p = P[j];
                const float g0 = Grow[p][0], g1 = Grow[p][1], g2 = Grow[p][2], g3 = Grow[p][3];
                out.x = g0*b1x + g1*b2x + g2*b3x;
                out.y = g0*b1y + g1*b2y + g2*b3y;
                out.z = g0*b1z + g1*b2z + g2*b3z;
                out.w = g0*px  + g1*py  + g2*pz  + g3;
            }
            Grow[j][0] = out.x; Grow[j][1] = out.y;
            Grow[j][2] = out.z; Grow[j][3] = out.w;

            // row into swizzled tile (uniform quad-bank spread per wave)
            stf[bl * 8 + ((jj * 4 + r) ^ (bl & 7))] = out;
        }

        __syncthreads();   // tile complete

        // flush: 4 KB = 32 full 128-B lines, wave-contiguous
        #pragma unroll
        for (int i = 0; i < 2; ++i) {
            int q  = i * TB + tid;            // [0, 256)
            int bp = q >> 3, s = q & 7;
            fvec4 v = stf[bp * 8 + (s ^ (bp & 7))];
            gtf4[(size_t)(b0 + bp) * 96 + t * 8 + s] = v;
        }

        __syncthreads();   // flush reads retired before next phase overwrites tile
    }

    // ---- epilogue: coords. Per-block output is perfectly linear (9216 B) ----
    if (r < 3) {
        #pragma unroll
        for (int j = 0; j < NJ; ++j)
            scoord[bl * 73 + j * 3 + r] = Grow[j][3];   // stride 73: bank-free
    }
    __syncthreads();
    #pragma unroll
    for (int i = 0; i < 9; ++i) {
        int fq = i * TB + tid;                // [0, 1152) fvec2
        int br = fq / 36, k2 = fq - br * 36;
        fvec2 v;
        v.x = scoord[br * 73 + 2 * k2 + 0];
        v.y = scoord[br * 73 + 2 * k2 + 1];
        gco2[(size_t)(b0 + br) * 36 + k2] = v;
    }
}

extern "C" void kernel_launch(void* const* d_in, const int* in_sizes, int n_in,
                              void* d_out, int out_size, void* d_ws, size_t ws_size,
                              hipStream_t stream) {
    const float* rot6 = (const float*)d_in[0];
    const float* pos  = (const float*)d_in[1];
    float* coords = (float*)d_out;                       // B*J*3
    float* tf     = (float*)d_out + (size_t)NB * NJ * 3; // B*J*16

    fk_kernel<<<dim3(NB / NBATCH), dim3(TB), 0, stream>>>(rot6, pos, coords, tf);
}